// Round 1
// baseline (114.070 us; speedup 1.0000x reference)
//
#include <hip/hip_runtime.h>

// Problem constants (from reference): B=2, T=256, C=384, head_dim=1 (384 scalar heads)
constexpr int B_ = 2, T_ = 256, C_ = 384;
constexpr int M_ = B_ * T_;  // 512 rows for the projection GEMMs
constexpr float SCALE = 0.051031036307982884f;  // 384^-0.5

constexpr int BM = 32, BN = 32, BK = 32;

// out[m,n] = sum_k x[m,k] * W[n,k] (+ bias[n])   — torch Linear: x @ W.T
// M=512, N=384, K=384. 32x32 tile, 256 threads, 2x2 per thread.
template <bool BIAS>
__device__ __forceinline__ void gemm_body(const float* __restrict__ x,
                                          const float* __restrict__ W,
                                          const float* __restrict__ bias,
                                          float* __restrict__ out) {
  __shared__ float As[BM][BK + 1];
  __shared__ float Bs[BN][BK + 1];
  const int t  = threadIdx.x;
  const int m0 = blockIdx.y * BM;
  const int n0 = blockIdx.x * BN;
  const int lr = t >> 3;         // 0..31 (row within tile)
  const int lc = (t & 7) << 2;   // 0,4,...,28 (col group, float4)
  const int tx = t & 15, ty = t >> 4;

  float acc00 = 0.f, acc01 = 0.f, acc10 = 0.f, acc11 = 0.f;

  for (int k0 = 0; k0 < C_; k0 += BK) {
    const float4 xa = *reinterpret_cast<const float4*>(&x[(m0 + lr) * C_ + k0 + lc]);
    const float4 wb = *reinterpret_cast<const float4*>(&W[(n0 + lr) * C_ + k0 + lc]);
    if (k0) __syncthreads();  // protect previous-iter LDS reads
    As[lr][lc] = xa.x; As[lr][lc + 1] = xa.y; As[lr][lc + 2] = xa.z; As[lr][lc + 3] = xa.w;
    Bs[lr][lc] = wb.x; Bs[lr][lc + 1] = wb.y; Bs[lr][lc + 2] = wb.z; Bs[lr][lc + 3] = wb.w;
    __syncthreads();
#pragma unroll
    for (int kk = 0; kk < BK; ++kk) {
      const float a0 = As[2 * ty][kk], a1 = As[2 * ty + 1][kk];
      const float b0 = Bs[2 * tx][kk], b1 = Bs[2 * tx + 1][kk];
      acc00 = fmaf(a0, b0, acc00);
      acc01 = fmaf(a0, b1, acc01);
      acc10 = fmaf(a1, b0, acc10);
      acc11 = fmaf(a1, b1, acc11);
    }
  }
  const int m = m0 + 2 * ty, n = n0 + 2 * tx;
  const float bs0 = BIAS ? bias[n] : 0.f;
  const float bs1 = BIAS ? bias[n + 1] : 0.f;
  out[m * C_ + n]           = acc00 + bs0;
  out[m * C_ + n + 1]       = acc01 + bs1;
  out[(m + 1) * C_ + n]     = acc10 + bs0;
  out[(m + 1) * C_ + n + 1] = acc11 + bs1;
}

// grid.z selects {q,k,v} projection (different x AND different W each).
__global__ __launch_bounds__(256) void qkv_gemm(
    const float* __restrict__ qin, const float* __restrict__ kin,
    const float* __restrict__ vin, const float* __restrict__ Wq,
    const float* __restrict__ Wk, const float* __restrict__ Wv,
    float* __restrict__ qo, float* __restrict__ ko, float* __restrict__ vo) {
  const float* x;
  const float* W;
  float* o;
  switch (blockIdx.z) {
    case 0:  x = qin; W = Wq; o = qo; break;
    case 1:  x = kin; W = Wk; o = ko; break;
    default: x = vin; W = Wv; o = vo; break;
  }
  gemm_body<false>(x, W, nullptr, o);
}

__global__ __launch_bounds__(256) void proj_gemm(const float* __restrict__ att,
                                                 const float* __restrict__ Wp,
                                                 const float* __restrict__ bpv,
                                                 float* __restrict__ out) {
  gemm_body<true>(att, Wp, bpv, out);
}

// One block per (b,i) output row; thread h = channel (= scalar head).
// Scores row i for head h: s_j = (q[b,i,h]*scale) * k[b,j,h], j<=i (causal).
// Two-pass softmax; loads coalesced across h (k[b,j,:] rows contiguous, L2-resident).
__global__ __launch_bounds__(C_) void attn_kernel(const float* __restrict__ q,
                                                  const float* __restrict__ k,
                                                  const float* __restrict__ v,
                                                  float* __restrict__ att) {
  const int h = threadIdx.x;
  const int b = blockIdx.x >> 8;        // / T_
  const int i = blockIdx.x & (T_ - 1);  // % T_
  const float* kb = k + b * T_ * C_ + h;
  const float* vb = v + b * T_ * C_ + h;
  const float a = q[(b * T_ + i) * C_ + h] * SCALE;

  float m = -3.4e38f;
#pragma unroll 4
  for (int j = 0; j <= i; ++j) m = fmaxf(m, a * kb[j * C_]);

  float den = 0.f, num = 0.f;
#pragma unroll 4
  for (int j = 0; j <= i; ++j) {
    const float p = __expf(a * kb[j * C_] - m);
    den += p;
    num = fmaf(p, vb[j * C_], num);
  }
  att[(b * T_ + i) * C_ + h] = num / den;
}

extern "C" void kernel_launch(void* const* d_in, const int* in_sizes, int n_in,
                              void* d_out, int out_size, void* d_ws, size_t ws_size,
                              hipStream_t stream) {
  const float* q_in = (const float*)d_in[0];
  const float* k_in = (const float*)d_in[1];
  const float* v_in = (const float*)d_in[2];
  // d_in[3] = mask (int32 tril) — known causal, handled via loop bound.
  const float* Wq = (const float*)d_in[4];
  const float* Wk = (const float*)d_in[5];
  const float* Wv = (const float*)d_in[6];
  const float* Wp = (const float*)d_in[7];
  const float* bp = (const float*)d_in[8];
  float* out = (float*)d_out;

  float* ws  = (float*)d_ws;
  float* q   = ws;                 // [512,384]
  float* k   = ws + M_ * C_;       // [512,384]
  float* v   = ws + 2 * M_ * C_;   // [512,384]
  float* att = ws + 3 * M_ * C_;   // [512,384]

  dim3 gqkv(C_ / BN, M_ / BM, 3);  // 12 x 16 x 3 = 576 blocks
  qkv_gemm<<<gqkv, 256, 0, stream>>>(q_in, k_in, v_in, Wq, Wk, Wv, q, k, v);

  attn_kernel<<<dim3(B_ * T_), C_, 0, stream>>>(q, k, v, att);  // 512 blocks x 384 thr

  dim3 gp(C_ / BN, M_ / BM);  // 12 x 16
  proj_gemm<<<gp, 256, 0, stream>>>(att, Wp, bp, out);
}

// Round 2
// 70.620 us; speedup vs baseline: 1.6153x; 1.6153x over previous
//
#include <hip/hip_runtime.h>

// B=2, T=256, C=384, head_dim=1 (384 scalar heads)
constexpr int B_ = 2, T_ = 256, C_ = 384;
constexpr int M_ = B_ * T_;
constexpr float SCALE = 0.051031036307982884f;  // 384^-0.5

// ---------------- GEMM: out = x @ W.T (+ bias). M=512, N=384, K=384 -------
// 64x64 tile, BK=16, 256 threads, 4x4 per thread, transposed LDS + float4 reads.
constexpr int GM = 64, GN = 64, GK = 16, GLD = 68;  // 68*4B = 272B row stride (16B aligned)

template <bool BIAS>
__device__ __forceinline__ void gemm64_body(const float* __restrict__ x,
                                            const float* __restrict__ W,
                                            const float* __restrict__ bias,
                                            float* __restrict__ out) {
  __shared__ float As[GK][GLD];
  __shared__ float Bs[GK][GLD];
  const int t  = threadIdx.x;
  const int m0 = blockIdx.y * GM;
  const int n0 = blockIdx.x * GN;
  const int lr = t >> 2;        // 0..63
  const int lc = (t & 3) << 2;  // 0,4,8,12
  const int tx = t & 15, ty = t >> 4;

  float acc[4][4] = {};

  const float* xr = x + (m0 + lr) * C_ + lc;
  const float* wr = W + (n0 + lr) * C_ + lc;

  for (int k0 = 0; k0 < C_; k0 += GK) {
    const float4 xa = *reinterpret_cast<const float4*>(xr + k0);
    const float4 wb = *reinterpret_cast<const float4*>(wr + k0);
    if (k0) __syncthreads();  // protect previous tile's LDS reads
    As[lc + 0][lr] = xa.x; As[lc + 1][lr] = xa.y; As[lc + 2][lr] = xa.z; As[lc + 3][lr] = xa.w;
    Bs[lc + 0][lr] = wb.x; Bs[lc + 1][lr] = wb.y; Bs[lc + 2][lr] = wb.z; Bs[lc + 3][lr] = wb.w;
    __syncthreads();
#pragma unroll
    for (int kk = 0; kk < GK; ++kk) {
      const float4 av = *reinterpret_cast<const float4*>(&As[kk][ty << 2]);
      const float4 bv = *reinterpret_cast<const float4*>(&Bs[kk][tx << 2]);
      const float aa[4] = {av.x, av.y, av.z, av.w};
      const float bb[4] = {bv.x, bv.y, bv.z, bv.w};
#pragma unroll
      for (int u = 0; u < 4; ++u)
#pragma unroll
        for (int w = 0; w < 4; ++w) acc[u][w] = fmaf(aa[u], bb[w], acc[u][w]);
    }
  }

  float4 bias4 = make_float4(0.f, 0.f, 0.f, 0.f);
  if (BIAS) bias4 = *reinterpret_cast<const float4*>(&bias[n0 + (tx << 2)]);
#pragma unroll
  for (int u = 0; u < 4; ++u) {
    float4 r;
    r.x = acc[u][0] + bias4.x;
    r.y = acc[u][1] + bias4.y;
    r.z = acc[u][2] + bias4.z;
    r.w = acc[u][3] + bias4.w;
    *reinterpret_cast<float4*>(&out[(m0 + (ty << 2) + u) * C_ + n0 + (tx << 2)]) = r;
  }
}

__global__ __launch_bounds__(256) void qkv_gemm(
    const float* __restrict__ qin, const float* __restrict__ kin,
    const float* __restrict__ vin, const float* __restrict__ Wq,
    const float* __restrict__ Wk, const float* __restrict__ Wv,
    float* __restrict__ qo, float* __restrict__ ko, float* __restrict__ vo) {
  const float* x;
  const float* W;
  float* o;
  switch (blockIdx.z) {
    case 0:  x = qin; W = Wq; o = qo; break;
    case 1:  x = kin; W = Wk; o = ko; break;
    default: x = vin; W = Wv; o = vo; break;
  }
  gemm64_body<false>(x, W, nullptr, o);
}

__global__ __launch_bounds__(256) void proj_gemm(const float* __restrict__ att,
                                                 const float* __restrict__ Wp,
                                                 const float* __restrict__ bpv,
                                                 float* __restrict__ out) {
  gemm64_body<true>(att, Wp, bpv, out);
}

// ---------------- Attention --------------------------------------------------
// head_dim=1: out[b,i,h] = sum_{j<=i} exp(q[b,i,h]*k[b,j,h]*scale) * v[b,j,h] / den.
// Scores are tiny (|s| < ~0.2) -> softmax WITHOUT max subtraction is exact-safe.
// Block = (b, p, channel-half): 4 rows {p, 127-p, 128+p, 255-p} -> every block
// does exactly 514 row-updates (perfect balance). 256 blocks x 192 threads.
#define ROW_UPD(ar, dr, nr, s)                 \
  {                                            \
    const float e = __expf((ar)*kj);           \
    dr[s] += e;                                \
    nr[s] = fmaf(e, vj, nr[s]);                \
  }

__global__ __launch_bounds__(192) void attn_kernel(const float* __restrict__ q,
                                                   const float* __restrict__ k,
                                                   const float* __restrict__ v,
                                                   float* __restrict__ att) {
  const int half = blockIdx.x & 1;
  const int p    = (blockIdx.x >> 1) & 63;
  const int b    = blockIdx.x >> 7;
  const int h    = half * 192 + threadIdx.x;
  const int i0 = p, i1 = 127 - p, i2 = 128 + p, i3 = 255 - p;

  const float* qb = q + b * T_ * C_ + h;
  const float* kb = k + b * T_ * C_ + h;
  const float* vb = v + b * T_ * C_ + h;
  const float a0 = qb[i0 * C_] * SCALE;
  const float a1 = qb[i1 * C_] * SCALE;
  const float a2 = qb[i2 * C_] * SCALE;
  const float a3 = qb[i3 * C_] * SCALE;

  float d0[2] = {0.f, 0.f}, n0[2] = {0.f, 0.f};
  float d1[2] = {0.f, 0.f}, n1[2] = {0.f, 0.f};
  float d2[2] = {0.f, 0.f}, n2[2] = {0.f, 0.f};
  float d3[2] = {0.f, 0.f}, n3[2] = {0.f, 0.f};

  int j = 0;
  // Phase A: j in [0, i0] -> rows 0,1,2,3
  for (; j + 3 <= i0; j += 4) {
#pragma unroll
    for (int u = 0; u < 4; ++u) {
      const float kj = kb[(j + u) * C_];
      const float vj = vb[(j + u) * C_];
      const int s = u & 1;
      ROW_UPD(a0, d0, n0, s) ROW_UPD(a1, d1, n1, s)
      ROW_UPD(a2, d2, n2, s) ROW_UPD(a3, d3, n3, s)
    }
  }
  for (; j <= i0; ++j) {
    const float kj = kb[j * C_], vj = vb[j * C_];
    ROW_UPD(a0, d0, n0, 0) ROW_UPD(a1, d1, n1, 0)
    ROW_UPD(a2, d2, n2, 0) ROW_UPD(a3, d3, n3, 0)
  }
  // Phase B: j in (i0, i1] -> rows 1,2,3
  for (; j + 3 <= i1; j += 4) {
#pragma unroll
    for (int u = 0; u < 4; ++u) {
      const float kj = kb[(j + u) * C_];
      const float vj = vb[(j + u) * C_];
      const int s = u & 1;
      ROW_UPD(a1, d1, n1, s) ROW_UPD(a2, d2, n2, s) ROW_UPD(a3, d3, n3, s)
    }
  }
  for (; j <= i1; ++j) {
    const float kj = kb[j * C_], vj = vb[j * C_];
    ROW_UPD(a1, d1, n1, 0) ROW_UPD(a2, d2, n2, 0) ROW_UPD(a3, d3, n3, 0)
  }
  // Phase C: j in (i1, i2] -> rows 2,3
  for (; j + 3 <= i2; j += 4) {
#pragma unroll
    for (int u = 0; u < 4; ++u) {
      const float kj = kb[(j + u) * C_];
      const float vj = vb[(j + u) * C_];
      const int s = u & 1;
      ROW_UPD(a2, d2, n2, s) ROW_UPD(a3, d3, n3, s)
    }
  }
  for (; j <= i2; ++j) {
    const float kj = kb[j * C_], vj = vb[j * C_];
    ROW_UPD(a2, d2, n2, 0) ROW_UPD(a3, d3, n3, 0)
  }
  // Phase D: j in (i2, i3] -> row 3
  for (; j + 3 <= i3; j += 4) {
#pragma unroll
    for (int u = 0; u < 4; ++u) {
      const float kj = kb[(j + u) * C_];
      const float vj = vb[(j + u) * C_];
      ROW_UPD(a3, d3, n3, u & 1)
    }
  }
  for (; j <= i3; ++j) {
    const float kj = kb[j * C_], vj = vb[j * C_];
    ROW_UPD(a3, d3, n3, 0)
  }

  const int base = b * T_ * C_ + h;
  att[base + i0 * C_] = (n0[0] + n0[1]) / (d0[0] + d0[1]);
  att[base + i1 * C_] = (n1[0] + n1[1]) / (d1[0] + d1[1]);
  att[base + i2 * C_] = (n2[0] + n2[1]) / (d2[0] + d2[1]);
  att[base + i3 * C_] = (n3[0] + n3[1]) / (d3[0] + d3[1]);
}

extern "C" void kernel_launch(void* const* d_in, const int* in_sizes, int n_in,
                              void* d_out, int out_size, void* d_ws, size_t ws_size,
                              hipStream_t stream) {
  const float* q_in = (const float*)d_in[0];
  const float* k_in = (const float*)d_in[1];
  const float* v_in = (const float*)d_in[2];
  // d_in[3] = mask (known causal tril) — handled via loop bounds.
  const float* Wq = (const float*)d_in[4];
  const float* Wk = (const float*)d_in[5];
  const float* Wv = (const float*)d_in[6];
  const float* Wp = (const float*)d_in[7];
  const float* bp = (const float*)d_in[8];
  float* out = (float*)d_out;

  float* ws  = (float*)d_ws;
  float* q   = ws;                // [512,384]
  float* k   = ws + M_ * C_;      // [512,384]
  float* v   = ws + 2 * M_ * C_;  // [512,384]
  float* att = ws + 3 * M_ * C_;  // [512,384]

  dim3 gqkv(C_ / GN, M_ / GM, 3);  // 6 x 8 x 3 = 144 blocks
  qkv_gemm<<<gqkv, 256, 0, stream>>>(q_in, k_in, v_in, Wq, Wk, Wv, q, k, v);

  attn_kernel<<<dim3(256), 192, 0, stream>>>(q, k, v, att);

  dim3 gp(C_ / GN, M_ / GM);  // 6 x 8
  proj_gemm<<<gp, 256, 0, stream>>>(att, Wp, bp, out);
}

// Round 3
// 48.267 us; speedup vs baseline: 2.3633x; 1.4631x over previous
//
#include <hip/hip_runtime.h>

// B=2, T=256, C=384, head_dim=1 (384 scalar heads)
constexpr int B_ = 2, T_ = 256, C_ = 384;
constexpr int M_ = B_ * T_;
constexpr float SCALE = 0.051031036307982884f;  // 384^-0.5

typedef __bf16 bf16x8 __attribute__((ext_vector_type(8)));
typedef float f32x4 __attribute__((ext_vector_type(4)));

// fp32 -> bf16 bits, round-to-nearest-even (inputs are finite/normal)
__device__ __forceinline__ unsigned short f2bf(float f) {
  unsigned int u = __float_as_uint(f);
  return (unsigned short)((u + 0x7FFFu + ((u >> 16) & 1u)) >> 16);
}

union BF8 {
  bf16x8 v;
  unsigned short u[8];
};

__device__ __forceinline__ bf16x8 load_frag(const float* __restrict__ p) {
  const float4 lo = *reinterpret_cast<const float4*>(p);
  const float4 hi = *reinterpret_cast<const float4*>(p + 4);
  BF8 r;
  r.u[0] = f2bf(lo.x); r.u[1] = f2bf(lo.y); r.u[2] = f2bf(lo.z); r.u[3] = f2bf(lo.w);
  r.u[4] = f2bf(hi.x); r.u[5] = f2bf(hi.y); r.u[6] = f2bf(hi.z); r.u[7] = f2bf(hi.w);
  return r.v;
}

// out[m,n] = sum_k x[m,k] * W[n,k] (+ bias[n])  via bf16 MFMA, fp32 accum.
// Block: 256 thr = 4 waves, 64x64 tile; wave = 32x32 (2x2 MFMA frags), K-loop step 32.
// A frag: lane holds x[m_base+am*16+(l&15)][k0+(l>>4)*8 .. +7]
// B frag: lane holds W[n_base+bn*16+(l&15)][same k range]  (B[k][n] = W[n][k])
// D: row=(l>>4)*4+reg, col=l&15  [m89-verified layout]
template <bool BIAS>
__device__ __forceinline__ void gemm_mfma_body(const float* __restrict__ x,
                                               const float* __restrict__ W,
                                               const float* __restrict__ bias,
                                               float* __restrict__ out) {
  const int t = threadIdx.x;
  const int wave = t >> 6;
  const int l = t & 63;
  const int r = l & 15;
  const int kq = (l >> 4) << 3;  // 0,8,16,24
  const int m_base = blockIdx.y * 64 + (wave >> 1) * 32;
  const int n_base = blockIdx.x * 64 + (wave & 1) * 32;

  f32x4 acc00 = {}, acc01 = {}, acc10 = {}, acc11 = {};

  const float* xp = x + (m_base + r) * C_ + kq;
  const float* wp = W + (n_base + r) * C_ + kq;

#pragma unroll 2
  for (int k0 = 0; k0 < C_; k0 += 32) {
    const bf16x8 a0 = load_frag(xp + k0);
    const bf16x8 a1 = load_frag(xp + 16 * C_ + k0);
    const bf16x8 b0 = load_frag(wp + k0);
    const bf16x8 b1 = load_frag(wp + 16 * C_ + k0);
    acc00 = __builtin_amdgcn_mfma_f32_16x16x32_bf16(a0, b0, acc00, 0, 0, 0);
    acc01 = __builtin_amdgcn_mfma_f32_16x16x32_bf16(a0, b1, acc01, 0, 0, 0);
    acc10 = __builtin_amdgcn_mfma_f32_16x16x32_bf16(a1, b0, acc10, 0, 0, 0);
    acc11 = __builtin_amdgcn_mfma_f32_16x16x32_bf16(a1, b1, acc11, 0, 0, 0);
  }

  const int row0 = (l >> 4) << 2;
  const int col = l & 15;
  const int n0c = n_base + col;
  const float bs0 = BIAS ? bias[n0c] : 0.f;
  const float bs1 = BIAS ? bias[n0c + 16] : 0.f;
#pragma unroll
  for (int reg = 0; reg < 4; ++reg) {
    const int m0r = (m_base + row0 + reg) * C_;
    out[m0r + n0c]            = acc00[reg] + bs0;
    out[m0r + n0c + 16]       = acc01[reg] + bs1;
    out[m0r + 16 * C_ + n0c]       = acc10[reg] + bs0;
    out[m0r + 16 * C_ + n0c + 16]  = acc11[reg] + bs1;
  }
}

__global__ __launch_bounds__(256) void qkv_gemm(
    const float* __restrict__ qin, const float* __restrict__ kin,
    const float* __restrict__ vin, const float* __restrict__ Wq,
    const float* __restrict__ Wk, const float* __restrict__ Wv,
    float* __restrict__ qo, float* __restrict__ ko, float* __restrict__ vo) {
  const float* x;
  const float* W;
  float* o;
  switch (blockIdx.z) {
    case 0:  x = qin; W = Wq; o = qo; break;
    case 1:  x = kin; W = Wk; o = ko; break;
    default: x = vin; W = Wv; o = vo; break;
  }
  gemm_mfma_body<false>(x, W, nullptr, o);
}

__global__ __launch_bounds__(256) void proj_gemm(const float* __restrict__ att,
                                                 const float* __restrict__ Wp,
                                                 const float* __restrict__ bpv,
                                                 float* __restrict__ out) {
  gemm_mfma_body<true>(att, Wp, bpv, out);
}

// ---------------- Attention -------------------------------------------------
// head_dim=1; scores tiny (|s|<~0.2) -> softmax without max subtraction exact.
// Block = (b, p, chunk): rows {p, 255-p} -> exactly 257 row-updates per block.
// 768 blocks x 128 threads (3 chunks of 128 channels) = 3 blocks/CU.
#define ROW_UPD(ar, dr, nr, s)       \
  {                                  \
    const float e = __expf((ar)*kj); \
    dr[s] += e;                      \
    nr[s] = fmaf(e, vj, nr[s]);      \
  }

__global__ __launch_bounds__(128) void attn_kernel(const float* __restrict__ q,
                                                   const float* __restrict__ k,
                                                   const float* __restrict__ v,
                                                   float* __restrict__ att) {
  const int chunk = blockIdx.x % 3;
  const int rest  = blockIdx.x / 3;
  const int p     = rest & 127;
  const int b     = rest >> 7;
  const int h     = chunk * 128 + threadIdx.x;
  const int i0 = p, i1 = 255 - p;

  const float* qb = q + b * T_ * C_ + h;
  const float* kb = k + b * T_ * C_ + h;
  const float* vb = v + b * T_ * C_ + h;
  const float a0 = qb[i0 * C_] * SCALE;
  const float a1 = qb[i1 * C_] * SCALE;

  float d0[2] = {0.f, 0.f}, n0[2] = {0.f, 0.f};
  float d1[2] = {0.f, 0.f}, n1[2] = {0.f, 0.f};

  int j = 0;
  // Phase A: j in [0, i0] -> both rows
  for (; j + 7 <= i0; j += 8) {
#pragma unroll
    for (int u = 0; u < 8; ++u) {
      const float kj = kb[(j + u) * C_];
      const float vj = vb[(j + u) * C_];
      const int s = u & 1;
      ROW_UPD(a0, d0, n0, s) ROW_UPD(a1, d1, n1, s)
    }
  }
  for (; j <= i0; ++j) {
    const float kj = kb[j * C_], vj = vb[j * C_];
    ROW_UPD(a0, d0, n0, 0) ROW_UPD(a1, d1, n1, 0)
  }
  // Phase B: j in (i0, i1] -> row 1 only
  for (; j + 7 <= i1; j += 8) {
#pragma unroll
    for (int u = 0; u < 8; ++u) {
      const float kj = kb[(j + u) * C_];
      const float vj = vb[(j + u) * C_];
      ROW_UPD(a1, d1, n1, u & 1)
    }
  }
  for (; j <= i1; ++j) {
    const float kj = kb[j * C_], vj = vb[j * C_];
    ROW_UPD(a1, d1, n1, 0)
  }

  const int base = b * T_ * C_ + h;
  att[base + i0 * C_] = (n0[0] + n0[1]) / (d0[0] + d0[1]);
  att[base + i1 * C_] = (n1[0] + n1[1]) / (d1[0] + d1[1]);
}

extern "C" void kernel_launch(void* const* d_in, const int* in_sizes, int n_in,
                              void* d_out, int out_size, void* d_ws, size_t ws_size,
                              hipStream_t stream) {
  const float* q_in = (const float*)d_in[0];
  const float* k_in = (const float*)d_in[1];
  const float* v_in = (const float*)d_in[2];
  // d_in[3] = mask (known causal tril) — handled via loop bounds.
  const float* Wq = (const float*)d_in[4];
  const float* Wk = (const float*)d_in[5];
  const float* Wv = (const float*)d_in[6];
  const float* Wp = (const float*)d_in[7];
  const float* bp = (const float*)d_in[8];
  float* out = (float*)d_out;

  float* ws  = (float*)d_ws;
  float* q   = ws;                // [512,384] f32
  float* k   = ws + M_ * C_;      // [512,384]
  float* v   = ws + 2 * M_ * C_;  // [512,384]
  float* att = ws + 3 * M_ * C_;  // [512,384]

  dim3 gqkv(C_ / 64, M_ / 64, 3);  // 6 x 8 x 3 = 144 blocks
  qkv_gemm<<<gqkv, 256, 0, stream>>>(q_in, k_in, v_in, Wq, Wk, Wv, q, k, v);

  attn_kernel<<<dim3(768), 128, 0, stream>>>(q, k, v, att);

  dim3 gp(C_ / 64, M_ / 64);  // 6 x 8
  proj_gemm<<<gp, 256, 0, stream>>>(att, Wp, bp, out);
}

// Round 4
// 38.202 us; speedup vs baseline: 2.9860x; 1.2635x over previous
//
#include <hip/hip_runtime.h>

// B=2, T=256, C=384, head_dim=1 (384 scalar heads)
constexpr int B_ = 2, T_ = 256, C_ = 384;
constexpr int M_ = B_ * T_;
constexpr float SCALE = 0.051031036307982884f;  // 384^-0.5

typedef __bf16 bf16x8 __attribute__((ext_vector_type(8)));
typedef float f32x4 __attribute__((ext_vector_type(4)));

// 8 fp32 -> bf16x8 via native casts (compiler emits v_cvt_pk_bf16_f32 pairs)
__device__ __forceinline__ bf16x8 cvt_frag(const float* __restrict__ p) {
  const float4 lo = *reinterpret_cast<const float4*>(p);
  const float4 hi = *reinterpret_cast<const float4*>(p + 4);
  bf16x8 r;
  r[0] = (__bf16)lo.x; r[1] = (__bf16)lo.y; r[2] = (__bf16)lo.z; r[3] = (__bf16)lo.w;
  r[4] = (__bf16)hi.x; r[5] = (__bf16)hi.y; r[6] = (__bf16)hi.z; r[7] = (__bf16)hi.w;
  return r;
}

// out[m,n] = sum_k A[m,k] * W[n,k] (+ bias), one 32x32 tile per 64-thread wave.
// A frag: lane l holds A[m0 + am*16 + (l&15)][k0 + (l>>4)*8 + e], e=0..7
// B frag: lane l holds W[n0 + bn*16 + (l&15)][same k]   (B[k][n] = W[n][k])
// D: row = (l>>4)*4 + reg, col = l&15  [m89-verified; round-3 validated]
template <bool BIAS, bool A_BF16>
__device__ __forceinline__ void gemm_wave(const void* __restrict__ xv,
                                          const float* __restrict__ W,
                                          const float* __restrict__ bias,
                                          float* __restrict__ out) {
  const int l = threadIdx.x & 63;
  const int r = l & 15;
  const int kq = (l >> 4) << 3;  // 0,8,16,24
  const int m0 = blockIdx.y * 32;
  const int n0 = blockIdx.x * 32;

  f32x4 acc00 = {}, acc01 = {}, acc10 = {}, acc11 = {};
  const float* wp = W + (n0 + r) * C_ + kq;

  if constexpr (A_BF16) {
    const __bf16* xp = (const __bf16*)xv + (m0 + r) * C_ + kq;
#pragma unroll 2
    for (int k0 = 0; k0 < C_; k0 += 32) {
      const bf16x8 a0 = *reinterpret_cast<const bf16x8*>(xp + k0);
      const bf16x8 a1 = *reinterpret_cast<const bf16x8*>(xp + 16 * C_ + k0);
      const bf16x8 b0 = cvt_frag(wp + k0);
      const bf16x8 b1 = cvt_frag(wp + 16 * C_ + k0);
      acc00 = __builtin_amdgcn_mfma_f32_16x16x32_bf16(a0, b0, acc00, 0, 0, 0);
      acc01 = __builtin_amdgcn_mfma_f32_16x16x32_bf16(a0, b1, acc01, 0, 0, 0);
      acc10 = __builtin_amdgcn_mfma_f32_16x16x32_bf16(a1, b0, acc10, 0, 0, 0);
      acc11 = __builtin_amdgcn_mfma_f32_16x16x32_bf16(a1, b1, acc11, 0, 0, 0);
    }
  } else {
    const float* xp = (const float*)xv + (m0 + r) * C_ + kq;
#pragma unroll 2
    for (int k0 = 0; k0 < C_; k0 += 32) {
      const bf16x8 a0 = cvt_frag(xp + k0);
      const bf16x8 a1 = cvt_frag(xp + 16 * C_ + k0);
      const bf16x8 b0 = cvt_frag(wp + k0);
      const bf16x8 b1 = cvt_frag(wp + 16 * C_ + k0);
      acc00 = __builtin_amdgcn_mfma_f32_16x16x32_bf16(a0, b0, acc00, 0, 0, 0);
      acc01 = __builtin_amdgcn_mfma_f32_16x16x32_bf16(a0, b1, acc01, 0, 0, 0);
      acc10 = __builtin_amdgcn_mfma_f32_16x16x32_bf16(a1, b0, acc10, 0, 0, 0);
      acc11 = __builtin_amdgcn_mfma_f32_16x16x32_bf16(a1, b1, acc11, 0, 0, 0);
    }
  }

  const int row0 = (l >> 4) << 2;
  const int col = l & 15;
  const int n0c = n0 + col;
  const float bs0 = BIAS ? bias[n0c] : 0.f;
  const float bs1 = BIAS ? bias[n0c + 16] : 0.f;
#pragma unroll
  for (int reg = 0; reg < 4; ++reg) {
    const int m0r = (m0 + row0 + reg) * C_;
    out[m0r + n0c]                = acc00[reg] + bs0;
    out[m0r + n0c + 16]           = acc01[reg] + bs1;
    out[m0r + 16 * C_ + n0c]      = acc10[reg] + bs0;
    out[m0r + 16 * C_ + n0c + 16] = acc11[reg] + bs1;
  }
}

__global__ __launch_bounds__(64) void qkv_gemm(
    const float* __restrict__ qin, const float* __restrict__ kin,
    const float* __restrict__ vin, const float* __restrict__ Wq,
    const float* __restrict__ Wk, const float* __restrict__ Wv,
    float* __restrict__ qo, float* __restrict__ ko, float* __restrict__ vo) {
  const float* x;
  const float* W;
  float* o;
  switch (blockIdx.z) {
    case 0:  x = qin; W = Wq; o = qo; break;
    case 1:  x = kin; W = Wk; o = ko; break;
    default: x = vin; W = Wv; o = vo; break;
  }
  gemm_wave<false, false>(x, W, nullptr, o);
}

__global__ __launch_bounds__(64) void proj_gemm(const __bf16* __restrict__ att,
                                                const float* __restrict__ Wp,
                                                const float* __restrict__ bpv,
                                                float* __restrict__ out) {
  gemm_wave<true, true>(att, Wp, bpv, out);
}

// ---------------- Attention -------------------------------------------------
// head_dim=1; |scores| < ~0.2 -> softmax without max subtraction is exact-safe.
// Block = (b, p, chunk): rows {p, 255-p} -> exactly 257 row-updates per block.
// 1536 blocks x 64 threads (6 chunks of 64 channels). Output stored as bf16
// (proj consumes bf16 A-fragments directly).
#define ROW_UPD(ar, dr, nr, s)       \
  {                                  \
    const float e = __expf((ar)*kj); \
    dr[s] += e;                      \
    nr[s] = fmaf(e, vj, nr[s]);      \
  }

__global__ __launch_bounds__(64) void attn_kernel(const float* __restrict__ q,
                                                  const float* __restrict__ k,
                                                  const float* __restrict__ v,
                                                  __bf16* __restrict__ att) {
  const int chunk = blockIdx.x % 6;
  const int rest  = blockIdx.x / 6;
  const int p     = rest & 127;
  const int b     = rest >> 7;
  const int h     = chunk * 64 + threadIdx.x;
  const int i0 = p, i1 = 255 - p;

  const float* qb = q + b * T_ * C_ + h;
  const float* kb = k + b * T_ * C_ + h;
  const float* vb = v + b * T_ * C_ + h;
  const float a0 = qb[i0 * C_] * SCALE;
  const float a1 = qb[i1 * C_] * SCALE;

  float d0[2] = {0.f, 0.f}, n0[2] = {0.f, 0.f};
  float d1[2] = {0.f, 0.f}, n1[2] = {0.f, 0.f};

  int j = 0;
  // Phase A: j in [0, i0] -> both rows
  for (; j + 7 <= i0; j += 8) {
#pragma unroll
    for (int u = 0; u < 8; ++u) {
      const float kj = kb[(j + u) * C_];
      const float vj = vb[(j + u) * C_];
      const int s = u & 1;
      ROW_UPD(a0, d0, n0, s) ROW_UPD(a1, d1, n1, s)
    }
  }
  for (; j <= i0; ++j) {
    const float kj = kb[j * C_], vj = vb[j * C_];
    ROW_UPD(a0, d0, n0, 0) ROW_UPD(a1, d1, n1, 0)
  }
  // Phase B: j in (i0, i1] -> row 1 only
  for (; j + 7 <= i1; j += 8) {
#pragma unroll
    for (int u = 0; u < 8; ++u) {
      const float kj = kb[(j + u) * C_];
      const float vj = vb[(j + u) * C_];
      ROW_UPD(a1, d1, n1, u & 1)
    }
  }
  for (; j <= i1; ++j) {
    const float kj = kb[j * C_], vj = vb[j * C_];
    ROW_UPD(a1, d1, n1, 0)
  }

  const int base = b * T_ * C_ + h;
  att[base + i0 * C_] = (__bf16)((n0[0] + n0[1]) / (d0[0] + d0[1]));
  att[base + i1 * C_] = (__bf16)((n1[0] + n1[1]) / (d1[0] + d1[1]));
}

extern "C" void kernel_launch(void* const* d_in, const int* in_sizes, int n_in,
                              void* d_out, int out_size, void* d_ws, size_t ws_size,
                              hipStream_t stream) {
  const float* q_in = (const float*)d_in[0];
  const float* k_in = (const float*)d_in[1];
  const float* v_in = (const float*)d_in[2];
  // d_in[3] = mask (known causal tril) — handled via loop bounds.
  const float* Wq = (const float*)d_in[4];
  const float* Wk = (const float*)d_in[5];
  const float* Wv = (const float*)d_in[6];
  const float* Wp = (const float*)d_in[7];
  const float* bp = (const float*)d_in[8];
  float* out = (float*)d_out;

  float* ws = (float*)d_ws;
  float* q  = ws;                 // [512,384] f32
  float* k  = ws + M_ * C_;       // [512,384] f32
  float* v  = ws + 2 * M_ * C_;   // [512,384] f32
  __bf16* att = (__bf16*)(ws + 3 * M_ * C_);  // [512,384] bf16 (16B-aligned)

  dim3 gqkv(C_ / 32, M_ / 32, 3);  // 12 x 16 x 3 = 576 wave-blocks
  qkv_gemm<<<gqkv, 64, 0, stream>>>(q_in, k_in, v_in, Wq, Wk, Wv, q, k, v);

  attn_kernel<<<dim3(1536), 64, 0, stream>>>(q, k, v, att);

  dim3 gp(C_ / 32, M_ / 32);  // 12 x 16 = 192 wave-blocks
  proj_gemm<<<gp, 64, 0, stream>>>(att, Wp, bp, out);
}